// Round 2
// baseline (245.325 us; speedup 1.0000x reference)
//
#include <hip/hip_runtime.h>

// Problem constants (fixed by the reference)
#define BATCH   262144
#define DDIM    128
#define GRID    2048
#define ROWS_PER_BLOCK 128      // BATCH / GRID
#define CHUNK   16              // rows staged per chunk
#define NCHUNK  8               // ROWS_PER_BLOCK / CHUNK
// blocks: j%3==0 dense, j%3==1 diagonal, j%3==2 lowrank; k = j/3.

// DPP helpers (VALU pipe): quad_perm xor1=0xB1, xor2=0x4E;
// row_half_mirror=0x141 (lane^7 after quad-sums), row_mirror=0x140 (lane^15).
template <int CTRL>
__device__ __forceinline__ float fdpp(float v) {
    int i = __builtin_bit_cast(int, v);
    i = __builtin_amdgcn_mov_dpp(i, CTRL, 0xF, 0xF, true);
    return __builtin_bit_cast(float, i);
}
// xor16 within each 32-lane half: ds_swizzle BitMode (16<<10)|0x1F
__device__ __forceinline__ float fswz16(float v) {
    int i = __builtin_bit_cast(int, v);
    i = __builtin_amdgcn_ds_swizzle(i, 0x401F);
    return __builtin_bit_cast(float, i);
}
// async global->LDS, 16B per lane (dest = wave-uniform base + lane*16)
__device__ __forceinline__ void gload_lds16(const float* g, float* l) {
    __builtin_amdgcn_global_load_lds(
        (const __attribute__((address_space(1))) void*)g,
        (__attribute__((address_space(3))) void*)l,
        16, 0, 0);
}

__global__ __launch_bounds__(256, 6) void bdla_kernel(
    const float* __restrict__ x,
    const float* __restrict__ Wd,   // [3,16,16]  W[k][o][d]
    const float* __restrict__ sd,   // [3,16]
    const float* __restrict__ U,    // [2,16,4]
    const float* __restrict__ V,    // [2,16,4]
    float* __restrict__ out)
{
    __shared__ float wlds[1072];            // 768 Wd | 48 sd | 128 U | 128 V
    __shared__ float xbuf[2][CHUNK * DDIM]; // 2 x 8 KB row tiles

    const int tid  = threadIdx.x;
    const int lane = tid & 63;
    const int w    = tid >> 6;        // wave id 0..3
    const int j    = lane >> 3;       // block id 0..7 (8 lanes per block)
    const int rot  = j >> 1;          // per-group chunk rotation (bank spread)
    const int o0   = 2 * (lane & 7);  // block-local output pair
    const int o1   = o0 + 1;

    // weights -> LDS (prologue only)
    for (int i = tid; i < 768; i += 256) wlds[i] = Wd[i];
    if (tid < 48)  wlds[768 + tid] = sd[tid];
    if (tid < 128) wlds[816 + tid] = U[tid];
    if (tid < 128) wlds[944 + tid] = V[tid];

    const size_t blockrow = (size_t)blockIdx.x * ROWS_PER_BLOCK;

    // stage chunk 0: each wave stages ONLY its own 4 rows (2KB = 2 calls)
    {
        const float* gs = x + (blockrow + w * 4) * DDIM;
        float* ls = &xbuf[0][w * 4 * DDIM];
        gload_lds16(gs + lane * 4,       ls + lane * 4);
        gload_lds16(gs + 256 + lane * 4, ls + 256 + lane * 4);
    }

    __syncthreads();   // drains vmcnt+lgkmcnt: weights AND chunk0 ready

    // Build the 32 per-lane weights B0/B1 (outputs o0,o1 of block j),
    // stored in this lane's rotated chunk order so hot-loop indices are static.
    float B0[16], B1[16];
    {
        const int mode = j % 3, k = j / 3;
        if (mode == 0) {
            const float* wm = &wlds[k * 256];
#pragma unroll
            for (int cc = 0; cc < 4; ++cc) {
                const int ce = (cc + rot) & 3;
#pragma unroll
                for (int e = 0; e < 4; ++e) {
                    B0[cc * 4 + e] = wm[o0 * 16 + ce * 4 + e];
                    B1[cc * 4 + e] = wm[o1 * 16 + ce * 4 + e];
                }
            }
        } else if (mode == 1) {
            const float* s = &wlds[768 + k * 16];
#pragma unroll
            for (int cc = 0; cc < 4; ++cc) {
                const int ce = (cc + rot) & 3;
#pragma unroll
                for (int e = 0; e < 4; ++e) {
                    const int d = ce * 4 + e;
                    B0[cc * 4 + e] = (d == o0) ? s[o0] : 0.0f;
                    B1[cc * 4 + e] = (d == o1) ? s[o1] : 0.0f;
                }
            }
        } else {
            const float* u = &wlds[816 + k * 64];
            const float* v = &wlds[944 + k * 64];
#pragma unroll
            for (int cc = 0; cc < 4; ++cc) {
                const int ce = (cc + rot) & 3;
#pragma unroll
                for (int e = 0; e < 4; ++e) {
                    const int d = ce * 4 + e;
                    float a0 = 0.f, a1 = 0.f;
#pragma unroll
                    for (int r = 0; r < 4; ++r) {
                        a0 += u[o0 * 4 + r] * v[d * 4 + r];
                        a1 += u[o1 * 4 + r] * v[d * 4 + r];
                    }
                    B0[cc * 4 + e] = a0;
                    B1[cc * 4 + e] = a1;
                }
            }
        }
    }
#pragma unroll
    for (int t = 0; t < 16; ++t) asm volatile("" : "+v"(B0[t]), "+v"(B1[t]));

    // Main loop: no barriers. Each wave reads only its own staged slice;
    // counted vmcnt keeps the next chunk's loads in flight (T3/T4 pattern).
#pragma unroll
    for (int c = 0; c < NCHUNK; ++c) {
        if (c + 1 < NCHUNK) {
            const float* gs = x + (blockrow + (size_t)(c + 1) * CHUNK + w * 4) * DDIM;
            float* ls = &xbuf[(c + 1) & 1][w * 4 * DDIM];
            gload_lds16(gs + lane * 4,       ls + lane * 4);
            gload_lds16(gs + 256 + lane * 4, ls + 256 + lane * 4);
        }
        // wait until this chunk's 2 staging ops have landed; keep next 2 in flight
        if (c + 1 < NCHUNK) asm volatile("s_waitcnt vmcnt(2)" ::: "memory");
        else                asm volatile("s_waitcnt vmcnt(0)" ::: "memory");

        const float* xb = &xbuf[c & 1][0];
#pragma unroll
        for (int pr = 0; pr < 2; ++pr) {
            const int r0 = w * 4 + pr * 2;
            const int r1 = r0 + 1;
            float y0a = 0.f, y1a = 0.f, y0b = 0.f, y1b = 0.f;
#pragma unroll
            for (int cc = 0; cc < 4; ++cc) {
                const int ce = (cc + rot) & 3;   // rotated: groups hit disjoint banks
                const float4 xa = *(const float4*)&xb[r0 * DDIM + j * 16 + ce * 4];
                const float4 xv = *(const float4*)&xb[r1 * DDIM + j * 16 + ce * 4];
                y0a = fmaf(B0[cc * 4 + 0], xa.x, y0a);
                y1a = fmaf(B1[cc * 4 + 0], xa.x, y1a);
                y0b = fmaf(B0[cc * 4 + 0], xv.x, y0b);
                y1b = fmaf(B1[cc * 4 + 0], xv.x, y1b);
                y0a = fmaf(B0[cc * 4 + 1], xa.y, y0a);
                y1a = fmaf(B1[cc * 4 + 1], xa.y, y1a);
                y0b = fmaf(B0[cc * 4 + 1], xv.y, y0b);
                y1b = fmaf(B1[cc * 4 + 1], xv.y, y1b);
                y0a = fmaf(B0[cc * 4 + 2], xa.z, y0a);
                y1a = fmaf(B1[cc * 4 + 2], xa.z, y1a);
                y0b = fmaf(B0[cc * 4 + 2], xv.z, y0b);
                y1b = fmaf(B1[cc * 4 + 2], xv.z, y1b);
                y0a = fmaf(B0[cc * 4 + 3], xa.w, y0a);
                y1a = fmaf(B1[cc * 4 + 3], xa.w, y1a);
                y0b = fmaf(B0[cc * 4 + 3], xv.w, y0b);
                y1b = fmaf(B1[cc * 4 + 3], xv.w, y1b);
            }

            // full-row (64-lane) L2-norm allreduce: 4 DPP + swizzle + xor32
            float ssa = y0a * y0a + y1a * y1a;
            float ssb = y0b * y0b + y1b * y1b;
            ssa += fdpp<0xB1>(ssa);  ssb += fdpp<0xB1>(ssb);   // +lane^1
            ssa += fdpp<0x4E>(ssa);  ssb += fdpp<0x4E>(ssb);   // +lane^2
            ssa += fdpp<0x141>(ssa); ssb += fdpp<0x141>(ssb);  // +lane^7
            ssa += fdpp<0x140>(ssa); ssb += fdpp<0x140>(ssb);  // +lane^15
            ssa += fswz16(ssa);      ssb += fswz16(ssb);       // +lane^16
            ssa += __shfl_xor(ssa, 32); ssb += __shfl_xor(ssb, 32); // +lane^32
            const float inva = 1.0f / (sqrtf(ssa) + 1e-8f);
            const float invb = 1.0f / (sqrtf(ssb) + 1e-8f);

            // lane writes its global output pair at column 2*lane
            float* po = out + (blockrow + (size_t)c * CHUNK + r0) * DDIM + 2 * lane;
            float2 oa, ob;
            oa.x = y0a * inva; oa.y = y1a * inva;
            ob.x = y0b * invb; ob.y = y1b * invb;
            *(float2*)po          = oa;
            *(float2*)(po + DDIM) = ob;
        }
    }
}

extern "C" void kernel_launch(void* const* d_in, const int* in_sizes, int n_in,
                              void* d_out, int out_size, void* d_ws, size_t ws_size,
                              hipStream_t stream) {
    const float* x  = (const float*)d_in[0];
    const float* Wd = (const float*)d_in[1];
    const float* sd = (const float*)d_in[2];
    const float* U  = (const float*)d_in[3];
    const float* V  = (const float*)d_in[4];
    float* out = (float*)d_out;
    (void)in_sizes; (void)n_in; (void)out_size; (void)d_ws; (void)ws_size;

    dim3 grid(GRID), block(256);
    hipLaunchKernelGGL(bdla_kernel, grid, block, 0, stream, x, Wd, sd, U, V, out);
}